// Round 15
// baseline (500.224 us; speedup 1.0000x reference)
//
#include <hip/hip_runtime.h>
#include <hip/hip_bf16.h>
#include <math.h>

// Problem constants (from reference)
#define LEN_TOT 21760
#define BATCH 2
#define MROWS (BATCH * LEN_TOT)   // 43520
#define DMODEL 256
#define DFFN 1024

typedef unsigned short ushort_t;
typedef __attribute__((ext_vector_type(8))) short short8;
typedef __attribute__((ext_vector_type(4))) short short4v;
typedef __attribute__((ext_vector_type(4))) float floatx4;
typedef __attribute__((address_space(3))) ushort_t lds_us;
typedef __attribute__((address_space(1))) const ushort_t glb_us;

// fp32 -> bf16 raw bits, round-to-nearest-even
__device__ __forceinline__ ushort_t f2b(float f) {
    unsigned u = __float_as_uint(f);
    unsigned r = (u + 0x7FFFu + ((u >> 16) & 1u)) >> 16;
    return (ushort_t)r;
}
// bf16 bits -> fp32
__device__ __forceinline__ float b2f(ushort_t u) {
    return __uint_as_float(((unsigned)u) << 16);
}

// tanh-form GELU via hardware exp; |err vs erf-GELU| ~3e-4, well under the
// bf16 output rounding (~4e-3) of every consumer of this value.
__device__ __forceinline__ float gelu_f(float x) {
    float x3 = x * x * x;
    float t = fmaf(x3, 0.035677408136f, x * 0.7978845608028654f);
    float e = __expf(2.0f * t);
    float th = 1.0f - 2.0f / (e + 1.0f);
    return 0.5f * x * (1.0f + th);
}

// m204 bijective XCD swizzle: consecutive hardware block ids round-robin
// across 8 XCDs; remap so each XCD owns a CONTIGUOUS range of work ids.
__device__ __forceinline__ int xcd_swizzle(int b, int n) {
    int q8 = n >> 3, r8 = n & 7;
    int xcd = b & 7, idx = b >> 3;
    return (xcd < r8 ? xcd * (q8 + 1) : r8 * (q8 + 1) + (xcd - r8) * q8) + idx;
}

// DPP cross-lane move (VALU pipe, not DS): row_ror:N -> CTRL = 0x120+N.
template<int CTRL>
__device__ __forceinline__ float dpp_f(float x) {
    return __int_as_float(__builtin_amdgcn_update_dpp(
        0, __float_as_int(x), CTRL, 0xF, 0xF, true));
}
// lane ^16 within each 32-lane group (DS pipe, 1 op, no index VALU)
__device__ __forceinline__ float swz16_f(float x) {
    return __int_as_float(__builtin_amdgcn_ds_swizzle(__float_as_int(x), 0x401F));
}

// ---------------------------------------------------------------------------
// Fused weight transpose + fp32->bf16 convert: W[K][N] f32 -> WT[N][K] bf16.
// ---------------------------------------------------------------------------
struct TP {
    const float* s[6];
    ushort_t*    d[6];
    int K[6];
    int N[6];
    int start[7];
};

__global__ __launch_bounds__(256) void transpose_convert(TP tp) {
    __shared__ float tile[32][33];
    int blk = blockIdx.x;
    int seg = 0;
    while (seg < 5 && blk >= tp.start[seg + 1]) seg++;
    int local = blk - tp.start[seg];
    int K = tp.K[seg], N = tp.N[seg];
    int tn = N >> 5;
    int k0 = (local / tn) << 5, n0 = (local % tn) << 5;
    int r = threadIdx.x >> 5, c = threadIdx.x & 31;
    const float* src = tp.s[seg];
    #pragma unroll
    for (int rr = r; rr < 32; rr += 8)
        tile[rr][c] = src[(size_t)(k0 + rr) * N + n0 + c];
    __syncthreads();
    ushort_t* dst = tp.d[seg];
    #pragma unroll
    for (int rr = r; rr < 32; rr += 8)
        dst[(size_t)(n0 + rr) * K + k0 + c] = f2b(tile[c][rr]);
}

// ---------------------------------------------------------------------------
// LayerNorm (+ optional pos add) -> bf16 output; optionally also emits
// bf16 copy of the raw input (for the un-normed value path).
// ---------------------------------------------------------------------------
__global__ __launch_bounds__(256) void ln_dual_kernel(
    const float* __restrict__ x, const float* __restrict__ g,
    const float* __restrict__ bb, const float* __restrict__ addv,
    ushort_t* __restrict__ y_bf, ushort_t* __restrict__ x_bf)
{
    int row  = blockIdx.x * 4 + (threadIdx.x >> 6);
    int lane = threadIdx.x & 63;
    size_t base = (size_t)row * DMODEL + lane * 4;
    float4 v = *(const float4*)(x + base);

    float s = v.x + v.y + v.z + v.w;
    #pragma unroll
    for (int o = 32; o; o >>= 1) s += __shfl_xor(s, o, 64);
    float mu = s * (1.0f / 256.0f);

    float d0 = v.x - mu, d1 = v.y - mu, d2 = v.z - mu, d3 = v.w - mu;
    float vs = d0*d0 + d1*d1 + d2*d2 + d3*d3;
    #pragma unroll
    for (int o = 32; o; o >>= 1) vs += __shfl_xor(vs, o, 64);
    float rstd = rsqrtf(vs * (1.0f / 256.0f) + 1e-5f);

    float4 gv = *(const float4*)(g  + lane * 4);
    float4 bv = *(const float4*)(bb + lane * 4);
    float o0 = d0 * rstd * gv.x + bv.x;
    float o1 = d1 * rstd * gv.y + bv.y;
    float o2 = d2 * rstd * gv.z + bv.z;
    float o3 = d3 * rstd * gv.w + bv.w;
    if (addv) {
        float4 av = *(const float4*)(addv + base);
        o0 += av.x; o1 += av.y; o2 += av.z; o3 += av.w;
    }
    ushort4 ob = {f2b(o0), f2b(o1), f2b(o2), f2b(o3)};
    *(ushort4*)(y_bf + base) = ob;
    if (x_bf) {
        ushort4 xb = {f2b(v.x), f2b(v.y), f2b(v.z), f2b(v.w)};
        *(ushort4*)(x_bf + base) = xb;
    }
}

// ---------------------------------------------------------------------------
// bf16 MFMA GEMM, 2-phase double-buffered staging (verified round 12).
// ---------------------------------------------------------------------------
template<int GELU_ACT, int HAS_RES, int OUT_BF16>
__global__ __launch_bounds__(256) void gemm_mfma(
    const ushort_t* __restrict__ A, const ushort_t* __restrict__ Bt,
    const float* __restrict__ bias, const float* __restrict__ bias2, int bsplit,
    const float* __restrict__ res,
    float* __restrict__ C, ushort_t* __restrict__ Cbf,
    int M, int N, int K, int NX)
{
    constexpr int BM = 128, BK = 32;
    __shared__ __align__(16) ushort_t As[2][BM * BK];   // 16 KB
    __shared__ __align__(16) ushort_t Bs[2][BM * BK];   // 16 KB

    const int tid  = threadIdx.x;
    const int wave = tid >> 6;
    const int lane = tid & 63;
    const int wm = (wave & 1) * 64;
    const int wn = (wave >> 1) * 64;
    const int ml = lane & 15;      // m (A) / n (B) / col (D)
    const int quad = lane >> 4;    // k-block for A/B; row-block for D
    const int w = xcd_swizzle(blockIdx.x, gridDim.x);
    const int bx = w % NX, by = w / NX;
    const int m0 = by * BM, n0 = bx * BM;

    const int r0 = tid >> 2, s0 = tid & 3;
    const int r1 = (tid + 256) >> 2;       // s1 == s0

    floatx4 acc[4][4] = {};

    auto stage = [&](int bsel, int k0) {
        const ushort_t* gA0 = A  + (size_t)(m0 + r0) * K + k0 + s0 * 8;
        const ushort_t* gA1 = A  + (size_t)(m0 + r1) * K + k0 + s0 * 8;
        const ushort_t* gB0 = Bt + (size_t)(n0 + r0) * K + k0 + s0 * 8;
        const ushort_t* gB1 = Bt + (size_t)(n0 + r1) * K + k0 + s0 * 8;
        __builtin_amdgcn_global_load_lds((glb_us*)gA0, (lds_us*)(As[bsel] + tid * 8),         16, 0, 0);
        __builtin_amdgcn_global_load_lds((glb_us*)gA1, (lds_us*)(As[bsel] + (tid + 256) * 8), 16, 0, 0);
        __builtin_amdgcn_global_load_lds((glb_us*)gB0, (lds_us*)(Bs[bsel] + tid * 8),         16, 0, 0);
        __builtin_amdgcn_global_load_lds((glb_us*)gB1, (lds_us*)(Bs[bsel] + (tid + 256) * 8), 16, 0, 0);
    };

    const int nt = K / BK;
    stage(0, 0);
    __syncthreads();

    int cur = 0;
    for (int t = 0; t < nt; ++t) {
        if (t + 1 < nt) stage(cur ^ 1, (t + 1) * BK);

        short8 af[4], bfr[4];
        #pragma unroll
        for (int i = 0; i < 4; i++)
            af[i] = *(const short8*)(As[cur] + (wm + i * 16 + ml) * BK + quad * 8);
        #pragma unroll
        for (int j = 0; j < 4; j++)
            bfr[j] = *(const short8*)(Bs[cur] + (wn + j * 16 + ml) * BK + quad * 8);
        #pragma unroll
        for (int i = 0; i < 4; i++)
            #pragma unroll
            for (int j = 0; j < 4; j++)
                acc[i][j] = __builtin_amdgcn_mfma_f32_16x16x32_bf16(
                    af[i], bfr[j], acc[i][j], 0, 0, 0);
        __syncthreads();
        cur ^= 1;
    }

    // Epilogue. D layout: col = lane&15, row = quad*4 + reg.
    if constexpr (OUT_BF16) {
        constexpr int EST = 76;
        ushort_t* wb = &As[0][0] + wave * (16 * EST + 8);
        const int lr  = lane >> 2;
        const int sg  = lane & 3;
        #pragma unroll
        for (int i = 0; i < 4; i++) {
            #pragma unroll
            for (int j = 0; j < 4; j++) {
                int col = n0 + wn + j * 16 + ml;
                float bc = (col < bsplit) ? bias[col] : bias2[col - bsplit];
                #pragma unroll
                for (int r = 0; r < 4; r++) {
                    float v = acc[i][j][r] + bc;
                    if (GELU_ACT) v = gelu_f(v);
                    if (HAS_RES)
                        v += res[(size_t)(m0 + wm + i * 16 + quad * 4 + r) * N
                                 + n0 + wn + j * 16 + ml];
                    wb[(quad * 4 + r) * EST + j * 16 + ml] = f2b(v);
                }
            }
            asm volatile("s_waitcnt lgkmcnt(0)" ::: "memory");
            #pragma unroll
            for (int h = 0; h < 2; h++) {
                int off = lr * EST + (sg + 4 * h) * 8;
                short4v lo = *(const short4v*)(wb + off);
                short4v hi = *(const short4v*)(wb + off + 4);
                short8 vv;
                vv[0] = lo[0]; vv[1] = lo[1]; vv[2] = lo[2]; vv[3] = lo[3];
                vv[4] = hi[0]; vv[5] = hi[1]; vv[6] = hi[2]; vv[7] = hi[3];
                *(short8*)(Cbf + (size_t)(m0 + wm + i * 16 + lr) * N
                                 + n0 + wn + (sg + 4 * h) * 8) = vv;
            }
        }
    } else {
        #pragma unroll
        for (int j = 0; j < 4; j++) {
            int col = n0 + wn + j * 16 + ml;
            float bc = (col < bsplit) ? bias[col] : bias2[col - bsplit];
            #pragma unroll
            for (int i = 0; i < 4; i++) {
                int row = m0 + wm + i * 16 + quad * 4;
                #pragma unroll
                for (int r = 0; r < 4; r++) {
                    float v = acc[i][j][r] + bc;
                    if (GELU_ACT) v = gelu_f(v);
                    if (HAS_RES) v += res[(size_t)(row + r) * N + col];
                    C[(size_t)(row + r) * N + col] = v;
                }
            }
        }
    }
}

// ---------------------------------------------------------------------------
// Fused FFN: out[M,256] = res + gelu(h0 @ Wf1 + b1) @ Wf2 + b2.
// Per 128x128 out-block, loop 8 chunks of 128 ffn-cols:
//   phase A: accT = h0_tile @ Wf1T[chunk] (2-phase dbuf, verified loop)
//            -> bias+gelu -> bf16 T in LDS [128][136] (16B-aligned rows)
//   phase B: accO += T @ Wf2T[n0-rows][chunk-cols] (T from LDS, Wf2 staged)
// h1 NEVER touches global memory (saves 178 MB round-trip vs steps 8+9).
// LDS: As/Bs dbuf 32 KB + Ts 34.8 KB = 67 KB -> 2 blocks/CU.
// ---------------------------------------------------------------------------
__global__ __launch_bounds__(256) void ffn_fused(
    const ushort_t* __restrict__ h0, const ushort_t* __restrict__ Wf1T,
    const float* __restrict__ b1, const ushort_t* __restrict__ Wf2T,
    const float* __restrict__ b2, const float* __restrict__ res,
    float* __restrict__ out, int M)
{
    constexpr int BM = 128, BK = 32, TST = 136;   // TST*2B = 272 = 16*17 (16B-aligned)
    __shared__ __align__(16) ushort_t As[2][BM * BK];   // 16 KB
    __shared__ __align__(16) ushort_t Bs[2][BM * BK];   // 16 KB
    __shared__ __align__(16) ushort_t Ts[BM * TST];     // 34.8 KB

    const int tid  = threadIdx.x;
    const int wave = tid >> 6;
    const int lane = tid & 63;
    const int wm = (wave & 1) * 64;
    const int wn = (wave >> 1) * 64;
    const int ml = lane & 15;
    const int quad = lane >> 4;
    const int w = xcd_swizzle(blockIdx.x, gridDim.x);
    const int bx = w % 2, by = w / 2;       // out N=256 -> NX=2
    const int m0 = by * BM, n0 = bx * BM;

    const int r0 = tid >> 2, s0 = tid & 3;
    const int r1 = (tid + 256) >> 2;

    floatx4 accO[4][4] = {};

    for (int c = 0; c < 8; ++c) {
        // ---- phase A: accT = h0_tile @ Wf1T[c*128 .. +128)  (K=256)
        floatx4 accT[4][4] = {};
        auto stageA = [&](int bsel, int k0) {
            const ushort_t* gA0 = h0 + (size_t)(m0 + r0) * 256 + k0 + s0 * 8;
            const ushort_t* gA1 = h0 + (size_t)(m0 + r1) * 256 + k0 + s0 * 8;
            const ushort_t* gB0 = Wf1T + (size_t)(c * 128 + r0) * 256 + k0 + s0 * 8;
            const ushort_t* gB1 = Wf1T + (size_t)(c * 128 + r1) * 256 + k0 + s0 * 8;
            __builtin_amdgcn_global_load_lds((glb_us*)gA0, (lds_us*)(As[bsel] + tid * 8),         16, 0, 0);
            __builtin_amdgcn_global_load_lds((glb_us*)gA1, (lds_us*)(As[bsel] + (tid + 256) * 8), 16, 0, 0);
            __builtin_amdgcn_global_load_lds((glb_us*)gB0, (lds_us*)(Bs[bsel] + tid * 8),         16, 0, 0);
            __builtin_amdgcn_global_load_lds((glb_us*)gB1, (lds_us*)(Bs[bsel] + (tid + 256) * 8), 16, 0, 0);
        };
        stageA(0, 0);
        __syncthreads();
        int cur = 0;
        #pragma unroll
        for (int t = 0; t < 8; ++t) {
            if (t + 1 < 8) stageA(cur ^ 1, (t + 1) * BK);
            short8 af[4], bfr[4];
            #pragma unroll
            for (int i = 0; i < 4; i++)
                af[i] = *(const short8*)(As[cur] + (wm + i * 16 + ml) * BK + quad * 8);
            #pragma unroll
            for (int j = 0; j < 4; j++)
                bfr[j] = *(const short8*)(Bs[cur] + (wn + j * 16 + ml) * BK + quad * 8);
            #pragma unroll
            for (int i = 0; i < 4; i++)
                #pragma unroll
                for (int j = 0; j < 4; j++)
                    accT[i][j] = __builtin_amdgcn_mfma_f32_16x16x32_bf16(
                        af[i], bfr[j], accT[i][j], 0, 0, 0);
            __syncthreads();
            cur ^= 1;
        }
        // bias + gelu -> bf16 T in LDS. D layout: col=ml, row=quad*4+r.
        #pragma unroll
        for (int i = 0; i < 4; i++)
            #pragma unroll
            for (int j = 0; j < 4; j++) {
                int col = wn + j * 16 + ml;             // 0..127 in-chunk
                float bc = b1[c * 128 + col];
                #pragma unroll
                for (int r = 0; r < 4; r++) {
                    float v = gelu_f(accT[i][j][r] + bc);
                    Ts[(wm + i * 16 + quad * 4 + r) * TST + col] = f2b(v);
                }
            }
        // stage first Wf2 slice while T-writes drain (Bs free: phase A done)
        auto stageB = [&](int bsel, int kk0) {
            const ushort_t* gB0 = Wf2T + (size_t)(n0 + r0) * 1024 + c * 128 + kk0 + s0 * 8;
            const ushort_t* gB1 = Wf2T + (size_t)(n0 + r1) * 1024 + c * 128 + kk0 + s0 * 8;
            __builtin_amdgcn_global_load_lds((glb_us*)gB0, (lds_us*)(Bs[bsel] + tid * 8),         16, 0, 0);
            __builtin_amdgcn_global_load_lds((glb_us*)gB1, (lds_us*)(Bs[bsel] + (tid + 256) * 8), 16, 0, 0);
        };
        stageB(0, 0);
        __syncthreads();   // orders T ds_writes (cross-wave) + drains stageB
        // ---- phase B: accO += T @ Wf2T-chunk  (K=128)
        cur = 0;
        #pragma unroll
        for (int tt = 0; tt < 4; ++tt) {
            if (tt + 1 < 4) stageB(cur ^ 1, (tt + 1) * BK);
            short8 af[4], bfr[4];
            #pragma unroll
            for (int i = 0; i < 4; i++)
                af[i] = *(const short8*)(Ts + (wm + i * 16 + ml) * TST + tt * BK + quad * 8);
            #pragma unroll
            for (int j = 0; j < 4; j++)
                bfr[j] = *(const short8*)(Bs[cur] + (wn + j * 16 + ml) * BK + quad * 8);
            #pragma unroll
            for (int i = 0; i < 4; i++)
                #pragma unroll
                for (int j = 0; j < 4; j++)
                    accO[i][j] = __builtin_amdgcn_mfma_f32_16x16x32_bf16(
                        af[i], bfr[j], accO[i][j], 0, 0, 0);
            __syncthreads();
            cur ^= 1;
        }
    }

    // epilogue: out = accO + b2 + res (fp32)
    #pragma unroll
    for (int j = 0; j < 4; j++) {
        int col = n0 + wn + j * 16 + ml;
        float bc = b2[col];
        #pragma unroll
        for (int i = 0; i < 4; i++) {
            int row = m0 + wm + i * 16 + quad * 4;
            #pragma unroll
            for (int r = 0; r < 4; r++) {
                out[(size_t)(row + r) * 256 + col] =
                    accO[i][j][r] + bc + res[(size_t)(row + r) * 256 + col];
            }
        }
    }
}

// ---------------------------------------------------------------------------
// Fused softmax + multi-scale deformable bilinear sampling, v7 (VERIFIED
// 95.2 us @ VALUBusy ~100%). Unchanged (control dispatch).
// ---------------------------------------------------------------------------
__global__ __launch_bounds__(256) void msdeform_kernel(
    const ushort_t* __restrict__ value, const float* __restrict__ comb,
    const float* __restrict__ refp, ushort_t* __restrict__ out_bf)
{
    int blk = xcd_swizzle(blockIdx.x, gridDim.x);
    int gid = blk * 8 + (threadIdx.x >> 5);  // (b*LEN + q)*8 + m
    int l   = threadIdx.x & 31;
    int bq  = gid >> 3;
    int m   = gid & 7;
    int b   = (bq >= LEN_TOT) ? 1 : 0;

    // ---- softmax over 16 logits via DPP rotation-reduce (rows of 16)
    int i = l & 15;
    float logit = comb[(size_t)bq * 384 + 256 + m * 16 + i];
    float mx = logit;
    mx = fmaxf(mx, dpp_f<0x128>(mx));
    mx = fmaxf(mx, dpp_f<0x124>(mx));
    mx = fmaxf(mx, dpp_f<0x122>(mx));
    mx = fmaxf(mx, dpp_f<0x121>(mx));
    float e = __expf(logit - mx);
    float se = e;
    se += dpp_f<0x128>(se);
    se += dpp_f<0x124>(se);
    se += dpp_f<0x122>(se);
    se += dpp_f<0x121>(se);
    float prob = e / se;

    const int ST_[4] = {0, 16384, 20480, 21504};
    const int sA = (l >> 2) & 7;
    const int cA = l & 3;
    const int dx = cA & 1, dy = cA >> 1;
    float probA = __shfl(prob, sA, 32);
    float probB = __shfl(prob, sA + 8, 32);

    int aA, aB; float hA, hB;
    #define CORNER(S, PROB, ADDR, WGT) { \
        int lvl = (S) >> 2; \
        int Wl = 128 >> lvl; float Wf = (float)Wl; \
        float2 off2 = ((const float2*)comb)[(size_t)bq * 192 + m * 16 + (S)]; \
        float2 ref2 = ((const float2*)refp)[(size_t)bq * 4 + lvl]; \
        float xs = fmaf(ref2.x, Wf, off2.x) - 0.5f; \
        float ys = fmaf(ref2.y, Wf, off2.y) - 0.5f; \
        float xf = floorf(xs), yf = floorf(ys); \
        int x0 = (int)xf, y0 = (int)yf; \
        float wx = xs - xf, wy = ys - yf; \
        int xc = x0 + dx, yc = y0 + dy; \
        bool v = (xc >= 0) & (xc < Wl) & (yc >= 0) & (yc < Wl); \
        int cx = min(max(xc, 0), Wl - 1); \
        int cy = min(max(yc, 0), Wl - 1); \
        ADDR = (b * LEN_TOT + ST_[lvl] + cy * Wl + cx) * 512 + m * 64; \
        float wxe = dx ? wx : 1.0f - wx; \
        float wye = dy ? wy : 1.0f - wy; \
        WGT = v ? (PROB) * wxe * wye : 0.0f; }
    CORNER(sA,     probA, aA, hA)
    CORNER(sA + 8, probB, aB, hB)
    #undef CORNER

    const int cl2 = l >> 2;
    const int dof = (l & 3) * 16;

    int p0 = __shfl(aA,      cl2, 32) + dof;
    int p1 = __shfl(aA,  8 + cl2, 32) + dof;
    int p2 = __shfl(aA, 16 + cl2, 32) + dof;
    int p3 = __shfl(aA, 24 + cl2, 32) + dof;
    int p4 = __shfl(aB,      cl2, 32) + dof;
    int p5 = __shfl(aB,  8 + cl2, 32) + dof;
    int p6 = __shfl(aB, 16 + cl2, 32) + dof;
    int p7 = __shfl(aB, 24 + cl2, 32) + dof;
    float h0 = __shfl(hA,      cl2, 32);
    float h1 = __shfl(hA,  8 + cl2, 32);
    float h2 = __shfl(hA, 16 + cl2, 32);
    float h3 = __shfl(hA, 24 + cl2, 32);
    float h4 = __shfl(hB,      cl2, 32);
    float h5 = __shfl(hB,  8 + cl2, 32);
    float h6 = __shfl(hB, 16 + cl2, 32);
    float h7 = __shfl(hB, 24 + cl2, 32);

    const char* vb = (const char*)value;
    uint4 v0 = *(const uint4*)(vb + p0);
    uint4 v1 = *(const uint4*)(vb + p1);
    uint4 v2 = *(const uint4*)(vb + p2);
    uint4 v3 = *(const uint4*)(vb + p3);
    uint4 v4 = *(const uint4*)(vb + p4);
    uint4 v5 = *(const uint4*)(vb + p5);
    uint4 v6 = *(const uint4*)(vb + p6);
    uint4 v7 = *(const uint4*)(vb + p7);

    float c0 = 0, c1 = 0, c2 = 0, c3 = 0, c4 = 0, c5 = 0, c6 = 0, c7 = 0;
    #define ACC8(V, H) \
        c0 = fmaf(H, __uint_as_float((V).x << 16),         c0); \
        c1 = fmaf(H, __uint_as_float((V).x & 0xffff0000u), c1); \
        c2 = fmaf(H, __uint_as_float((V).y << 16),         c2); \
        c3 = fmaf(H, __uint_as_float((V).y & 0xffff0000u), c3); \
        c4 = fmaf(H, __uint_as_float((V).z << 16),         c4); \
        c5 = fmaf(H, __uint_as_float((V).z & 0xffff0000u), c5); \
        c6 = fmaf(H, __uint_as_float((V).w << 16),         c6); \
        c7 = fmaf(H, __uint_as_float((V).w & 0xffff0000u), c7);
    ACC8(v0, h0) ACC8(v1, h1) ACC8(v2, h2) ACC8(v3, h3)
    ACC8(v4, h4) ACC8(v5, h5) ACC8(v6, h6) ACC8(v7, h7)
    #undef ACC8

    c0 += dpp_f<0x124>(c0); c1 += dpp_f<0x124>(c1);
    c2 += dpp_f<0x124>(c2); c3 += dpp_f<0x124>(c3);
    c4 += dpp_f<0x124>(c4); c5 += dpp_f<0x124>(c5);
    c6 += dpp_f<0x124>(c6); c7 += dpp_f<0x124>(c7);
    c0 += dpp_f<0x128>(c0); c1 += dpp_f<0x128>(c1);
    c2 += dpp_f<0x128>(c2); c3 += dpp_f<0x128>(c3);
    c4 += dpp_f<0x128>(c4); c5 += dpp_f<0x128>(c5);
    c6 += dpp_f<0x128>(c6); c7 += dpp_f<0x128>(c7);
    c0 += swz16_f(c0); c1 += swz16_f(c1);
    c2 += swz16_f(c2); c3 += swz16_f(c3);
    c4 += swz16_f(c4); c5 += swz16_f(c5);
    c6 += swz16_f(c6); c7 += swz16_f(c7);

    if (l < 4) {
        short8 ov;
        ov[0] = (short)f2b(c0); ov[1] = (short)f2b(c1);
        ov[2] = (short)f2b(c2); ov[3] = (short)f2b(c3);
        ov[4] = (short)f2b(c4); ov[5] = (short)f2b(c5);
        ov[6] = (short)f2b(c6); ov[7] = (short)f2b(c7);
        *(short8*)(out_bf + (size_t)gid * 32 + l * 8) = ov;
    }
}

// ---------------------------------------------------------------------------
// kernel_launch — workspace layout (round-2 verified); h1_bf eliminated
// (FFN fused; src_bf/comb regions simply dead after step 7).
// ---------------------------------------------------------------------------
extern "C" void kernel_launch(void* const* d_in, const int* in_sizes, int n_in,
                              void* d_out, int out_size, void* d_ws, size_t ws_size,
                              hipStream_t stream)
{
    const float* src  = (const float*)d_in[0];
    const float* pos  = (const float*)d_in[1];
    const float* refp = (const float*)d_in[2];
    const float* n1g = (const float*)d_in[5];
    const float* n1b = (const float*)d_in[6];
    const float* n2g = (const float*)d_in[7];
    const float* n2b = (const float*)d_in[8];
    const float* Wv  = (const float*)d_in[9];
    const float* bv  = (const float*)d_in[10];
    const float* Wof = (const float*)d_in[11];
    const float* bof = (const float*)d_in[12];
    const float* Wat = (const float*)d_in[13];
    const float* bat = (const float*)d_in[14];
    const float* Wo  = (const float*)d_in[15];
    const float* bo  = (const float*)d_in[16];
    const float* Wf1 = (const float*)d_in[17];
    const float* bf1 = (const float*)d_in[18];
    const float* Wf2 = (const float*)d_in[19];
    const float* bf2 = (const float*)d_in[20];
    float* out = (float*)d_out;

    char* ws = (char*)d_ws;
    const int M = MROWS;               // 43520
    const size_t SZ_BF = (size_t)M * 256 * 2;   // 22,282,240
    const size_t SZ_F  = (size_t)M * 256 * 4;   // 44,564,480
    const int BIG = 1 << 30;

    ushort_t* q_bf    = (ushort_t*)(ws);                              // [M,256] bf16
    ushort_t* value_b = (ushort_t*)(ws + SZ_BF);                      // [M,256] bf16 (region sized SZ_F)
    ushort_t* src_bf  = (ushort_t*)(ws + SZ_BF + SZ_F);               // [M,256] bf16
    float*    comb    = (float*)   (ws + 2 * SZ_BF + SZ_F);           // [M,384] f32 (offs | logits)
    ushort_t* h0_bf   = q_bf;
    ushort_t* sampled = src_bf;
    float*    src2    = (float*)   (ws + SZ_BF);                      // overwrites value_b after step 5
    char* wtp = ws + 2 * SZ_BF + 2 * SZ_F + (size_t)M * 128 * 4;
    ushort_t* WvT  = (ushort_t*)(wtp);
    ushort_t* WofT = WvT  + 256 * 256;   // [256][256]
    ushort_t* WatT = WofT + 256 * 256;   // [128][256]  (contiguous => [384][256])
    ushort_t* WoT  = WatT + 256 * 128;
    ushort_t* Wf1T = WoT  + 256 * 256;
    ushort_t* Wf2T = Wf1T + 256 * 1024;

    // 0) transpose+convert all weights to [N][K] bf16
    TP tp;
    tp.s[0] = Wv;  tp.d[0] = WvT;  tp.K[0] = 256;  tp.N[0] = 256;
    tp.s[1] = Wof; tp.d[1] = WofT; tp.K[1] = 256;  tp.N[1] = 256;
    tp.s[2] = Wat; tp.d[2] = WatT; tp.K[2] = 256;  tp.N[2] = 128;
    tp.s[3] = Wo;  tp.d[3] = WoT;  tp.K[3] = 256;  tp.N[3] = 256;
    tp.s[4] = Wf1; tp.d[4] = Wf1T; tp.K[4] = 256;  tp.N[4] = 1024;
    tp.s[5] = Wf2; tp.d[5] = Wf2T; tp.K[5] = 1024; tp.N[5] = 256;
    tp.start[0] = 0;   tp.start[1] = 64;  tp.start[2] = 128;
    tp.start[3] = 160; tp.start[4] = 224; tp.start[5] = 480; tp.start[6] = 736;
    transpose_convert<<<736, 256, 0, stream>>>(tp);

    // 1) q_bf = bf16(LN1(src) + pos); src_bf = bf16(src)
    ln_dual_kernel<<<M / 4, 256, 0, stream>>>(src, n1g, n1b, pos, q_bf, src_bf);
    // 2) value_b = bf16(src_bf @ Wv + bv)   [row-major M x 256]
    gemm_mfma<0, 0, 1><<<2 * (M / 128), 256, 0, stream>>>(
        src_bf, WvT, bv, bv, BIG, nullptr, nullptr, value_b, M, 256, 256, 2);
    // 3+4) comb = q_bf @ [Wof|Wat] + [bof|bat]   (fp32, N=384 fused)
    gemm_mfma<0, 0, 0><<<3 * (M / 128), 256, 0, stream>>>(
        q_bf, WofT, bof, bat, 256, nullptr, comb, nullptr, M, 384, 256, 3);
    // 5) fused softmax + sampling -> sampled (bf16; comb dead after)
    msdeform_kernel<<<M, 256, 0, stream>>>(value_b, comb, refp, sampled);
    // 6) src2 = sampled @ Wo + bo + src  (fp32, overwrites value_b)
    gemm_mfma<0, 1, 0><<<2 * (M / 128), 256, 0, stream>>>(
        sampled, WoT, bo, bo, BIG, src, src2, nullptr, M, 256, 256, 2);
    // 7) h0_bf = bf16(LN2(src2))
    ln_dual_kernel<<<M / 4, 256, 0, stream>>>(src2, n2g, n2b, nullptr, h0_bf, nullptr);
    // 8+9 fused) out = src2 + gelu(h0 @ Wf1 + b1) @ Wf2 + b2
    ffn_fused<<<2 * (M / 128), 256, 0, stream>>>(
        h0_bf, Wf1T, bf1, Wf2T, bf2, src2, out, M);
}

// Round 16
// 435.960 us; speedup vs baseline: 1.1474x; 1.1474x over previous
//
#include <hip/hip_runtime.h>
#include <hip/hip_bf16.h>
#include <math.h>

// Problem constants (from reference)
#define LEN_TOT 21760
#define BATCH 2
#define MROWS (BATCH * LEN_TOT)   // 43520
#define DMODEL 256
#define DFFN 1024

typedef unsigned short ushort_t;
typedef __attribute__((ext_vector_type(8))) short short8;
typedef __attribute__((ext_vector_type(4))) short short4v;
typedef __attribute__((ext_vector_type(4))) float floatx4;
typedef __attribute__((address_space(3))) ushort_t lds_us;
typedef __attribute__((address_space(1))) const ushort_t glb_us;

// fp32 -> bf16 raw bits, round-to-nearest-even
__device__ __forceinline__ ushort_t f2b(float f) {
    unsigned u = __float_as_uint(f);
    unsigned r = (u + 0x7FFFu + ((u >> 16) & 1u)) >> 16;
    return (ushort_t)r;
}
// bf16 bits -> fp32
__device__ __forceinline__ float b2f(ushort_t u) {
    return __uint_as_float(((unsigned)u) << 16);
}

// tanh-form GELU via hardware exp; |err vs erf-GELU| ~3e-4, well under the
// bf16 output rounding (~4e-3) of every consumer of this value.
__device__ __forceinline__ float gelu_f(float x) {
    float x3 = x * x * x;
    float t = fmaf(x3, 0.035677408136f, x * 0.7978845608028654f);
    float e = __expf(2.0f * t);
    float th = 1.0f - 2.0f / (e + 1.0f);
    return 0.5f * x * (1.0f + th);
}

// m204 bijective XCD swizzle: consecutive hardware block ids round-robin
// across 8 XCDs; remap so each XCD owns a CONTIGUOUS range of work ids.
__device__ __forceinline__ int xcd_swizzle(int b, int n) {
    int q8 = n >> 3, r8 = n & 7;
    int xcd = b & 7, idx = b >> 3;
    return (xcd < r8 ? xcd * (q8 + 1) : r8 * (q8 + 1) + (xcd - r8) * q8) + idx;
}

// DPP cross-lane move (VALU pipe, not DS): row_ror:N -> CTRL = 0x120+N.
template<int CTRL>
__device__ __forceinline__ float dpp_f(float x) {
    return __int_as_float(__builtin_amdgcn_update_dpp(
        0, __float_as_int(x), CTRL, 0xF, 0xF, true));
}
// lane ^16 within each 32-lane group (DS pipe, 1 op, no index VALU)
__device__ __forceinline__ float swz16_f(float x) {
    return __int_as_float(__builtin_amdgcn_ds_swizzle(__float_as_int(x), 0x401F));
}

// ---------------------------------------------------------------------------
// Fused weight transpose + fp32->bf16 convert: W[K][N] f32 -> WT[N][K] bf16.
// ---------------------------------------------------------------------------
struct TP {
    const float* s[6];
    ushort_t*    d[6];
    int K[6];
    int N[6];
    int start[7];
};

__global__ __launch_bounds__(256) void transpose_convert(TP tp) {
    __shared__ float tile[32][33];
    int blk = blockIdx.x;
    int seg = 0;
    while (seg < 5 && blk >= tp.start[seg + 1]) seg++;
    int local = blk - tp.start[seg];
    int K = tp.K[seg], N = tp.N[seg];
    int tn = N >> 5;
    int k0 = (local / tn) << 5, n0 = (local % tn) << 5;
    int r = threadIdx.x >> 5, c = threadIdx.x & 31;
    const float* src = tp.s[seg];
    #pragma unroll
    for (int rr = r; rr < 32; rr += 8)
        tile[rr][c] = src[(size_t)(k0 + rr) * N + n0 + c];
    __syncthreads();
    ushort_t* dst = tp.d[seg];
    #pragma unroll
    for (int rr = r; rr < 32; rr += 8)
        dst[(size_t)(n0 + rr) * K + k0 + c] = f2b(tile[c][rr]);
}

// ---------------------------------------------------------------------------
// LayerNorm (+ optional pos add) -> bf16 output; optionally also emits
// bf16 copy of the raw input (for the un-normed value path).
// ---------------------------------------------------------------------------
__global__ __launch_bounds__(256) void ln_dual_kernel(
    const float* __restrict__ x, const float* __restrict__ g,
    const float* __restrict__ bb, const float* __restrict__ addv,
    ushort_t* __restrict__ y_bf, ushort_t* __restrict__ x_bf)
{
    int row  = blockIdx.x * 4 + (threadIdx.x >> 6);
    int lane = threadIdx.x & 63;
    size_t base = (size_t)row * DMODEL + lane * 4;
    float4 v = *(const float4*)(x + base);

    float s = v.x + v.y + v.z + v.w;
    #pragma unroll
    for (int o = 32; o; o >>= 1) s += __shfl_xor(s, o, 64);
    float mu = s * (1.0f / 256.0f);

    float d0 = v.x - mu, d1 = v.y - mu, d2 = v.z - mu, d3 = v.w - mu;
    float vs = d0*d0 + d1*d1 + d2*d2 + d3*d3;
    #pragma unroll
    for (int o = 32; o; o >>= 1) vs += __shfl_xor(vs, o, 64);
    float rstd = rsqrtf(vs * (1.0f / 256.0f) + 1e-5f);

    float4 gv = *(const float4*)(g  + lane * 4);
    float4 bv = *(const float4*)(bb + lane * 4);
    float o0 = d0 * rstd * gv.x + bv.x;
    float o1 = d1 * rstd * gv.y + bv.y;
    float o2 = d2 * rstd * gv.z + bv.z;
    float o3 = d3 * rstd * gv.w + bv.w;
    if (addv) {
        float4 av = *(const float4*)(addv + base);
        o0 += av.x; o1 += av.y; o2 += av.z; o3 += av.w;
    }
    ushort4 ob = {f2b(o0), f2b(o1), f2b(o2), f2b(o3)};
    *(ushort4*)(y_bf + base) = ob;
    if (x_bf) {
        ushort4 xb = {f2b(v.x), f2b(v.y), f2b(v.z), f2b(v.w)};
        *(ushort4*)(x_bf + base) = xb;
    }
}

// ---------------------------------------------------------------------------
// bf16 MFMA GEMM, 2-phase double-buffered staging (verified round 12).
// ---------------------------------------------------------------------------
template<int GELU_ACT, int HAS_RES, int OUT_BF16>
__global__ __launch_bounds__(256) void gemm_mfma(
    const ushort_t* __restrict__ A, const ushort_t* __restrict__ Bt,
    const float* __restrict__ bias, const float* __restrict__ bias2, int bsplit,
    const float* __restrict__ res,
    float* __restrict__ C, ushort_t* __restrict__ Cbf,
    int M, int N, int K, int NX)
{
    constexpr int BM = 128, BK = 32;
    __shared__ __align__(16) ushort_t As[2][BM * BK];   // 16 KB
    __shared__ __align__(16) ushort_t Bs[2][BM * BK];   // 16 KB

    const int tid  = threadIdx.x;
    const int wave = tid >> 6;
    const int lane = tid & 63;
    const int wm = (wave & 1) * 64;
    const int wn = (wave >> 1) * 64;
    const int ml = lane & 15;      // m (A) / n (B) / col (D)
    const int quad = lane >> 4;    // k-block for A/B; row-block for D
    const int w = xcd_swizzle(blockIdx.x, gridDim.x);
    const int bx = w % NX, by = w / NX;
    const int m0 = by * BM, n0 = bx * BM;

    const int r0 = tid >> 2, s0 = tid & 3;
    const int r1 = (tid + 256) >> 2;       // s1 == s0

    floatx4 acc[4][4] = {};

    auto stage = [&](int bsel, int k0) {
        const ushort_t* gA0 = A  + (size_t)(m0 + r0) * K + k0 + s0 * 8;
        const ushort_t* gA1 = A  + (size_t)(m0 + r1) * K + k0 + s0 * 8;
        const ushort_t* gB0 = Bt + (size_t)(n0 + r0) * K + k0 + s0 * 8;
        const ushort_t* gB1 = Bt + (size_t)(n0 + r1) * K + k0 + s0 * 8;
        __builtin_amdgcn_global_load_lds((glb_us*)gA0, (lds_us*)(As[bsel] + tid * 8),         16, 0, 0);
        __builtin_amdgcn_global_load_lds((glb_us*)gA1, (lds_us*)(As[bsel] + (tid + 256) * 8), 16, 0, 0);
        __builtin_amdgcn_global_load_lds((glb_us*)gB0, (lds_us*)(Bs[bsel] + tid * 8),         16, 0, 0);
        __builtin_amdgcn_global_load_lds((glb_us*)gB1, (lds_us*)(Bs[bsel] + (tid + 256) * 8), 16, 0, 0);
    };

    const int nt = K / BK;
    stage(0, 0);
    __syncthreads();

    int cur = 0;
    for (int t = 0; t < nt; ++t) {
        if (t + 1 < nt) stage(cur ^ 1, (t + 1) * BK);

        short8 af[4], bfr[4];
        #pragma unroll
        for (int i = 0; i < 4; i++)
            af[i] = *(const short8*)(As[cur] + (wm + i * 16 + ml) * BK + quad * 8);
        #pragma unroll
        for (int j = 0; j < 4; j++)
            bfr[j] = *(const short8*)(Bs[cur] + (wn + j * 16 + ml) * BK + quad * 8);
        #pragma unroll
        for (int i = 0; i < 4; i++)
            #pragma unroll
            for (int j = 0; j < 4; j++)
                acc[i][j] = __builtin_amdgcn_mfma_f32_16x16x32_bf16(
                    af[i], bfr[j], acc[i][j], 0, 0, 0);
        __syncthreads();
        cur ^= 1;
    }

    // Epilogue. D layout: col = lane&15, row = quad*4 + reg.
    if constexpr (OUT_BF16) {
        constexpr int EST = 76;
        ushort_t* wb = &As[0][0] + wave * (16 * EST + 8);
        const int lr  = lane >> 2;
        const int sg  = lane & 3;
        #pragma unroll
        for (int i = 0; i < 4; i++) {
            #pragma unroll
            for (int j = 0; j < 4; j++) {
                int col = n0 + wn + j * 16 + ml;
                float bc = (col < bsplit) ? bias[col] : bias2[col - bsplit];
                #pragma unroll
                for (int r = 0; r < 4; r++) {
                    float v = acc[i][j][r] + bc;
                    if (GELU_ACT) v = gelu_f(v);
                    if (HAS_RES)
                        v += res[(size_t)(m0 + wm + i * 16 + quad * 4 + r) * N
                                 + n0 + wn + j * 16 + ml];
                    wb[(quad * 4 + r) * EST + j * 16 + ml] = f2b(v);
                }
            }
            asm volatile("s_waitcnt lgkmcnt(0)" ::: "memory");
            #pragma unroll
            for (int h = 0; h < 2; h++) {
                int off = lr * EST + (sg + 4 * h) * 8;
                short4v lo = *(const short4v*)(wb + off);
                short4v hi = *(const short4v*)(wb + off + 4);
                short8 vv;
                vv[0] = lo[0]; vv[1] = lo[1]; vv[2] = lo[2]; vv[3] = lo[3];
                vv[4] = hi[0]; vv[5] = hi[1]; vv[6] = hi[2]; vv[7] = hi[3];
                *(short8*)(Cbf + (size_t)(m0 + wm + i * 16 + lr) * N
                                 + n0 + wn + (sg + 4 * h) * 8) = vv;
            }
        }
    } else {
        #pragma unroll
        for (int j = 0; j < 4; j++) {
            int col = n0 + wn + j * 16 + ml;
            float bc = (col < bsplit) ? bias[col] : bias2[col - bsplit];
            #pragma unroll
            for (int i = 0; i < 4; i++) {
                int row = m0 + wm + i * 16 + quad * 4;
                #pragma unroll
                for (int r = 0; r < 4; r++) {
                    float v = acc[i][j][r] + bc;
                    if (GELU_ACT) v = gelu_f(v);
                    if (HAS_RES) v += res[(size_t)(row + r) * N + col];
                    C[(size_t)(row + r) * N + col] = v;
                }
            }
        }
    }
}

// ---------------------------------------------------------------------------
// Fused softmax + multi-scale deformable bilinear sampling, v7 (VERIFIED
// 95.2 us @ VALUBusy ~100% — DS 64->26 confirmed the DS-pipe theory).
// Unchanged (control dispatch).
// ---------------------------------------------------------------------------
__global__ __launch_bounds__(256) void msdeform_kernel(
    const ushort_t* __restrict__ value, const float* __restrict__ comb,
    const float* __restrict__ refp, ushort_t* __restrict__ out_bf)
{
    int blk = xcd_swizzle(blockIdx.x, gridDim.x);
    int gid = blk * 8 + (threadIdx.x >> 5);  // (b*LEN + q)*8 + m
    int l   = threadIdx.x & 31;
    int bq  = gid >> 3;
    int m   = gid & 7;
    int b   = (bq >= LEN_TOT) ? 1 : 0;

    // ---- softmax over 16 logits via DPP rotation-reduce (rows of 16)
    int i = l & 15;
    float logit = comb[(size_t)bq * 384 + 256 + m * 16 + i];
    float mx = logit;
    mx = fmaxf(mx, dpp_f<0x128>(mx));
    mx = fmaxf(mx, dpp_f<0x124>(mx));
    mx = fmaxf(mx, dpp_f<0x122>(mx));
    mx = fmaxf(mx, dpp_f<0x121>(mx));
    float e = __expf(logit - mx);
    float se = e;
    se += dpp_f<0x128>(se);
    se += dpp_f<0x124>(se);
    se += dpp_f<0x122>(se);
    se += dpp_f<0x121>(se);
    float prob = e / se;

    const int ST_[4] = {0, 16384, 20480, 21504};
    const int sA = (l >> 2) & 7;
    const int cA = l & 3;
    const int dx = cA & 1, dy = cA >> 1;
    float probA = __shfl(prob, sA, 32);
    float probB = __shfl(prob, sA + 8, 32);

    int aA, aB; float hA, hB;
    #define CORNER(S, PROB, ADDR, WGT) { \
        int lvl = (S) >> 2; \
        int Wl = 128 >> lvl; float Wf = (float)Wl; \
        float2 off2 = ((const float2*)comb)[(size_t)bq * 192 + m * 16 + (S)]; \
        float2 ref2 = ((const float2*)refp)[(size_t)bq * 4 + lvl]; \
        float xs = fmaf(ref2.x, Wf, off2.x) - 0.5f; \
        float ys = fmaf(ref2.y, Wf, off2.y) - 0.5f; \
        float xf = floorf(xs), yf = floorf(ys); \
        int x0 = (int)xf, y0 = (int)yf; \
        float wx = xs - xf, wy = ys - yf; \
        int xc = x0 + dx, yc = y0 + dy; \
        bool v = (xc >= 0) & (xc < Wl) & (yc >= 0) & (yc < Wl); \
        int cx = min(max(xc, 0), Wl - 1); \
        int cy = min(max(yc, 0), Wl - 1); \
        ADDR = (b * LEN_TOT + ST_[lvl] + cy * Wl + cx) * 512 + m * 64; \
        float wxe = dx ? wx : 1.0f - wx; \
        float wye = dy ? wy : 1.0f - wy; \
        WGT = v ? (PROB) * wxe * wye : 0.0f; }
    CORNER(sA,     probA, aA, hA)
    CORNER(sA + 8, probB, aB, hB)
    #undef CORNER

    const int cl2 = l >> 2;
    const int dof = (l & 3) * 16;

    int p0 = __shfl(aA,      cl2, 32) + dof;
    int p1 = __shfl(aA,  8 + cl2, 32) + dof;
    int p2 = __shfl(aA, 16 + cl2, 32) + dof;
    int p3 = __shfl(aA, 24 + cl2, 32) + dof;
    int p4 = __shfl(aB,      cl2, 32) + dof;
    int p5 = __shfl(aB,  8 + cl2, 32) + dof;
    int p6 = __shfl(aB, 16 + cl2, 32) + dof;
    int p7 = __shfl(aB, 24 + cl2, 32) + dof;
    float h0 = __shfl(hA,      cl2, 32);
    float h1 = __shfl(hA,  8 + cl2, 32);
    float h2 = __shfl(hA, 16 + cl2, 32);
    float h3 = __shfl(hA, 24 + cl2, 32);
    float h4 = __shfl(hB,      cl2, 32);
    float h5 = __shfl(hB,  8 + cl2, 32);
    float h6 = __shfl(hB, 16 + cl2, 32);
    float h7 = __shfl(hB, 24 + cl2, 32);

    const char* vb = (const char*)value;
    uint4 v0 = *(const uint4*)(vb + p0);
    uint4 v1 = *(const uint4*)(vb + p1);
    uint4 v2 = *(const uint4*)(vb + p2);
    uint4 v3 = *(const uint4*)(vb + p3);
    uint4 v4 = *(const uint4*)(vb + p4);
    uint4 v5 = *(const uint4*)(vb + p5);
    uint4 v6 = *(const uint4*)(vb + p6);
    uint4 v7 = *(const uint4*)(vb + p7);

    float c0 = 0, c1 = 0, c2 = 0, c3 = 0, c4 = 0, c5 = 0, c6 = 0, c7 = 0;
    #define ACC8(V, H) \
        c0 = fmaf(H, __uint_as_float((V).x << 16),         c0); \
        c1 = fmaf(H, __uint_as_float((V).x & 0xffff0000u), c1); \
        c2 = fmaf(H, __uint_as_float((V).y << 16),         c2); \
        c3 = fmaf(H, __uint_as_float((V).y & 0xffff0000u), c3); \
        c4 = fmaf(H, __uint_as_float((V).z << 16),         c4); \
        c5 = fmaf(H, __uint_as_float((V).z & 0xffff0000u), c5); \
        c6 = fmaf(H, __uint_as_float((V).w << 16),         c6); \
        c7 = fmaf(H, __uint_as_float((V).w & 0xffff0000u), c7);
    ACC8(v0, h0) ACC8(v1, h1) ACC8(v2, h2) ACC8(v3, h3)
    ACC8(v4, h4) ACC8(v5, h5) ACC8(v6, h6) ACC8(v7, h7)
    #undef ACC8

    c0 += dpp_f<0x124>(c0); c1 += dpp_f<0x124>(c1);
    c2 += dpp_f<0x124>(c2); c3 += dpp_f<0x124>(c3);
    c4 += dpp_f<0x124>(c4); c5 += dpp_f<0x124>(c5);
    c6 += dpp_f<0x124>(c6); c7 += dpp_f<0x124>(c7);
    c0 += dpp_f<0x128>(c0); c1 += dpp_f<0x128>(c1);
    c2 += dpp_f<0x128>(c2); c3 += dpp_f<0x128>(c3);
    c4 += dpp_f<0x128>(c4); c5 += dpp_f<0x128>(c5);
    c6 += dpp_f<0x128>(c6); c7 += dpp_f<0x128>(c7);
    c0 += swz16_f(c0); c1 += swz16_f(c1);
    c2 += swz16_f(c2); c3 += swz16_f(c3);
    c4 += swz16_f(c4); c5 += swz16_f(c5);
    c6 += swz16_f(c6); c7 += swz16_f(c7);

    if (l < 4) {
        short8 ov;
        ov[0] = (short)f2b(c0); ov[1] = (short)f2b(c1);
        ov[2] = (short)f2b(c2); ov[3] = (short)f2b(c3);
        ov[4] = (short)f2b(c4); ov[5] = (short)f2b(c5);
        ov[6] = (short)f2b(c6); ov[7] = (short)f2b(c7);
        *(short8*)(out_bf + (size_t)gid * 32 + l * 8) = ov;
    }
}

// ---------------------------------------------------------------------------
// kernel_launch — workspace layout (round-2 verified):
//   [q_bf | value(bf16, region sized f32) | src_bf | comb | weights]
//   h1_bf == src_bf..(spans src_bf + comb regions exactly, all dead by then)
// ---------------------------------------------------------------------------
extern "C" void kernel_launch(void* const* d_in, const int* in_sizes, int n_in,
                              void* d_out, int out_size, void* d_ws, size_t ws_size,
                              hipStream_t stream)
{
    const float* src  = (const float*)d_in[0];
    const float* pos  = (const float*)d_in[1];
    const float* refp = (const float*)d_in[2];
    const float* n1g = (const float*)d_in[5];
    const float* n1b = (const float*)d_in[6];
    const float* n2g = (const float*)d_in[7];
    const float* n2b = (const float*)d_in[8];
    const float* Wv  = (const float*)d_in[9];
    const float* bv  = (const float*)d_in[10];
    const float* Wof = (const float*)d_in[11];
    const float* bof = (const float*)d_in[12];
    const float* Wat = (const float*)d_in[13];
    const float* bat = (const float*)d_in[14];
    const float* Wo  = (const float*)d_in[15];
    const float* bo  = (const float*)d_in[16];
    const float* Wf1 = (const float*)d_in[17];
    const float* bf1 = (const float*)d_in[18];
    const float* Wf2 = (const float*)d_in[19];
    const float* bf2 = (const float*)d_in[20];
    float* out = (float*)d_out;

    char* ws = (char*)d_ws;
    const int M = MROWS;               // 43520
    const size_t SZ_BF = (size_t)M * 256 * 2;   // 22,282,240
    const size_t SZ_F  = (size_t)M * 256 * 4;   // 44,564,480
    const int BIG = 1 << 30;

    ushort_t* q_bf    = (ushort_t*)(ws);                              // [M,256] bf16
    ushort_t* value_b = (ushort_t*)(ws + SZ_BF);                      // [M,256] bf16 (region sized SZ_F)
    ushort_t* src_bf  = (ushort_t*)(ws + SZ_BF + SZ_F);               // [M,256] bf16
    float*    comb    = (float*)   (ws + 2 * SZ_BF + SZ_F);           // [M,384] f32 (offs | logits)
    ushort_t* h0_bf   = q_bf;
    ushort_t* sampled = src_bf;
    float*    src2    = (float*)   (ws + SZ_BF);                      // overwrites value_b after step 5
    ushort_t* h1_bf   = src_bf;   // [M,1024] bf16, spans src_bf + comb exactly
    char* wtp = ws + 2 * SZ_BF + 2 * SZ_F + (size_t)M * 128 * 4;
    ushort_t* WvT  = (ushort_t*)(wtp);
    ushort_t* WofT = WvT  + 256 * 256;   // [256][256]
    ushort_t* WatT = WofT + 256 * 256;   // [128][256]  (contiguous => [384][256])
    ushort_t* WoT  = WatT + 256 * 128;
    ushort_t* Wf1T = WoT  + 256 * 256;
    ushort_t* Wf2T = Wf1T + 256 * 1024;

    // 0) transpose+convert all weights to [N][K] bf16
    TP tp;
    tp.s[0] = Wv;  tp.d[0] = WvT;  tp.K[0] = 256;  tp.N[0] = 256;
    tp.s[1] = Wof; tp.d[1] = WofT; tp.K[1] = 256;  tp.N[1] = 256;
    tp.s[2] = Wat; tp.d[2] = WatT; tp.K[2] = 256;  tp.N[2] = 128;
    tp.s[3] = Wo;  tp.d[3] = WoT;  tp.K[3] = 256;  tp.N[3] = 256;
    tp.s[4] = Wf1; tp.d[4] = Wf1T; tp.K[4] = 256;  tp.N[4] = 1024;
    tp.s[5] = Wf2; tp.d[5] = Wf2T; tp.K[5] = 1024; tp.N[5] = 256;
    tp.start[0] = 0;   tp.start[1] = 64;  tp.start[2] = 128;
    tp.start[3] = 160; tp.start[4] = 224; tp.start[5] = 480; tp.start[6] = 736;
    transpose_convert<<<736, 256, 0, stream>>>(tp);

    // 1) q_bf = bf16(LN1(src) + pos); src_bf = bf16(src)
    ln_dual_kernel<<<M / 4, 256, 0, stream>>>(src, n1g, n1b, pos, q_bf, src_bf);
    // 2) value_b = bf16(src_bf @ Wv + bv)   [row-major M x 256]
    gemm_mfma<0, 0, 1><<<2 * (M / 128), 256, 0, stream>>>(
        src_bf, WvT, bv, bv, BIG, nullptr, nullptr, value_b, M, 256, 256, 2);
    // 3+4) comb = q_bf @ [Wof|Wat] + [bof|bat]   (fp32, N=384 fused)
    gemm_mfma<0, 0, 0><<<3 * (M / 128), 256, 0, stream>>>(
        q_bf, WofT, bof, bat, 256, nullptr, comb, nullptr, M, 384, 256, 3);
    // 5) fused softmax + sampling -> sampled (bf16; comb dead after)
    msdeform_kernel<<<M, 256, 0, stream>>>(value_b, comb, refp, sampled);
    // 6) src2 = sampled @ Wo + bo + src  (fp32, overwrites value_b)
    gemm_mfma<0, 1, 0><<<2 * (M / 128), 256, 0, stream>>>(
        sampled, WoT, bo, bo, BIG, src, src2, nullptr, M, 256, 256, 2);
    // 7) h0_bf = bf16(LN2(src2))
    ln_dual_kernel<<<M / 4, 256, 0, stream>>>(src2, n2g, n2b, nullptr, h0_bf, nullptr);
    // 8) h1_bf = bf16(gelu(h0_bf @ Wf1 + bf1))  (overlays sampled+comb, all dead)
    gemm_mfma<1, 0, 1><<<8 * (M / 128), 256, 0, stream>>>(
        h0_bf, Wf1T, bf1, bf1, BIG, nullptr, nullptr, h1_bf, M, 1024, 256, 8);
    // 9) out = h1_bf @ Wf2 + bf2 + src2  (fp32)
    gemm_mfma<0, 1, 0><<<2 * (M / 128), 256, 0, stream>>>(
        h1_bf, Wf2T, bf2, bf2, BIG, src2, out, nullptr, M, 256, 1024, 2);
}

// Round 18
// 425.916 us; speedup vs baseline: 1.1745x; 1.0236x over previous
//
#include <hip/hip_runtime.h>
#include <hip/hip_bf16.h>
#include <math.h>

// Problem constants (from reference)
#define LEN_TOT 21760
#define BATCH 2
#define MROWS (BATCH * LEN_TOT)   // 43520
#define DMODEL 256
#define DFFN 1024

typedef unsigned short ushort_t;
typedef __attribute__((ext_vector_type(8))) short short8;
typedef __attribute__((ext_vector_type(4))) short short4v;
typedef __attribute__((ext_vector_type(4))) float floatx4;
typedef __attribute__((address_space(3))) ushort_t lds_us;
typedef __attribute__((address_space(1))) const ushort_t glb_us;

// fp32 -> bf16 raw bits, round-to-nearest-even
__device__ __forceinline__ ushort_t f2b(float f) {
    unsigned u = __float_as_uint(f);
    unsigned r = (u + 0x7FFFu + ((u >> 16) & 1u)) >> 16;
    return (ushort_t)r;
}
// bf16 bits -> fp32
__device__ __forceinline__ float b2f(ushort_t u) {
    return __uint_as_float(((unsigned)u) << 16);
}

// tanh-form GELU via hardware exp; |err vs erf-GELU| ~3e-4, well under the
// bf16 output rounding (~4e-3) of every consumer of this value.
__device__ __forceinline__ float gelu_f(float x) {
    float x3 = x * x * x;
    float t = fmaf(x3, 0.035677408136f, x * 0.7978845608028654f);
    float e = __expf(2.0f * t);
    float th = 1.0f - 2.0f / (e + 1.0f);
    return 0.5f * x * (1.0f + th);
}

// m204 bijective XCD swizzle: consecutive hardware block ids round-robin
// across 8 XCDs; remap so each XCD owns a CONTIGUOUS range of work ids.
__device__ __forceinline__ int xcd_swizzle(int b, int n) {
    int q8 = n >> 3, r8 = n & 7;
    int xcd = b & 7, idx = b >> 3;
    return (xcd < r8 ? xcd * (q8 + 1) : r8 * (q8 + 1) + (xcd - r8) * q8) + idx;
}

// DPP cross-lane move (VALU pipe, not DS): row_ror:N -> CTRL = 0x120+N.
template<int CTRL>
__device__ __forceinline__ float dpp_f(float x) {
    return __int_as_float(__builtin_amdgcn_update_dpp(
        0, __float_as_int(x), CTRL, 0xF, 0xF, true));
}
// lane ^16 within each 32-lane group (DS pipe, 1 op, no index VALU)
__device__ __forceinline__ float swz16_f(float x) {
    return __int_as_float(__builtin_amdgcn_ds_swizzle(__float_as_int(x), 0x401F));
}

// ---------------------------------------------------------------------------
// Fused weight transpose + fp32->bf16 convert: W[K][N] f32 -> WT[N][K] bf16.
// ---------------------------------------------------------------------------
struct TP {
    const float* s[6];
    ushort_t*    d[6];
    int K[6];
    int N[6];
    int start[7];
};

__global__ __launch_bounds__(256) void transpose_convert(TP tp) {
    __shared__ float tile[32][33];
    int blk = blockIdx.x;
    int seg = 0;
    while (seg < 5 && blk >= tp.start[seg + 1]) seg++;
    int local = blk - tp.start[seg];
    int K = tp.K[seg], N = tp.N[seg];
    int tn = N >> 5;
    int k0 = (local / tn) << 5, n0 = (local % tn) << 5;
    int r = threadIdx.x >> 5, c = threadIdx.x & 31;
    const float* src = tp.s[seg];
    #pragma unroll
    for (int rr = r; rr < 32; rr += 8)
        tile[rr][c] = src[(size_t)(k0 + rr) * N + n0 + c];
    __syncthreads();
    ushort_t* dst = tp.d[seg];
    #pragma unroll
    for (int rr = r; rr < 32; rr += 8)
        dst[(size_t)(n0 + rr) * K + k0 + c] = f2b(tile[c][rr]);
}

// ---------------------------------------------------------------------------
// LayerNorm (+ optional pos add) -> bf16 output; optionally also emits
// bf16 copy of the raw input (for the un-normed value path).
// ---------------------------------------------------------------------------
__global__ __launch_bounds__(256) void ln_dual_kernel(
    const float* __restrict__ x, const float* __restrict__ g,
    const float* __restrict__ bb, const float* __restrict__ addv,
    ushort_t* __restrict__ y_bf, ushort_t* __restrict__ x_bf)
{
    int row  = blockIdx.x * 4 + (threadIdx.x >> 6);
    int lane = threadIdx.x & 63;
    size_t base = (size_t)row * DMODEL + lane * 4;
    float4 v = *(const float4*)(x + base);

    float s = v.x + v.y + v.z + v.w;
    #pragma unroll
    for (int o = 32; o; o >>= 1) s += __shfl_xor(s, o, 64);
    float mu = s * (1.0f / 256.0f);

    float d0 = v.x - mu, d1 = v.y - mu, d2 = v.z - mu, d3 = v.w - mu;
    float vs = d0*d0 + d1*d1 + d2*d2 + d3*d3;
    #pragma unroll
    for (int o = 32; o; o >>= 1) vs += __shfl_xor(vs, o, 64);
    float rstd = rsqrtf(vs * (1.0f / 256.0f) + 1e-5f);

    float4 gv = *(const float4*)(g  + lane * 4);
    float4 bv = *(const float4*)(bb + lane * 4);
    float o0 = d0 * rstd * gv.x + bv.x;
    float o1 = d1 * rstd * gv.y + bv.y;
    float o2 = d2 * rstd * gv.z + bv.z;
    float o3 = d3 * rstd * gv.w + bv.w;
    if (addv) {
        float4 av = *(const float4*)(addv + base);
        o0 += av.x; o1 += av.y; o2 += av.z; o3 += av.w;
    }
    ushort4 ob = {f2b(o0), f2b(o1), f2b(o2), f2b(o3)};
    *(ushort4*)(y_bf + base) = ob;
    if (x_bf) {
        ushort4 xb = {f2b(v.x), f2b(v.y), f2b(v.z), f2b(v.w)};
        *(ushort4*)(x_bf + base) = xb;
    }
}

// ---------------------------------------------------------------------------
// bf16 MFMA GEMM body, 2-phase double-buffered staging (verified round 12).
// LDS is declared by the CALLING kernel and passed in (so a merged kernel's
// multiple template instantiations share one allocation).
// As/Bs: [2][BM*BK] flattened. w: pre-swizzled 1D work id.
// ---------------------------------------------------------------------------
template<int GELU_ACT, int HAS_RES, int OUT_BF16>
__device__ __forceinline__ void gemm_body(
    ushort_t* As, ushort_t* Bs,
    const ushort_t* __restrict__ A, const ushort_t* __restrict__ Bt,
    const float* __restrict__ bias, const float* __restrict__ bias2, int bsplit,
    const float* __restrict__ res,
    float* __restrict__ C, ushort_t* __restrict__ Cbf,
    int M, int N, int K, int NX, int w)
{
    constexpr int BM = 128, BK = 32;
    constexpr int BUF = BM * BK;           // 4096 shorts = 8 KB

    const int tid  = threadIdx.x;
    const int wave = tid >> 6;
    const int lane = tid & 63;
    const int wm = (wave & 1) * 64;
    const int wn = (wave >> 1) * 64;
    const int ml = lane & 15;      // m (A) / n (B) / col (D)
    const int quad = lane >> 4;    // k-block for A/B; row-block for D
    const int bx = w % NX, by = w / NX;
    const int m0 = by * BM, n0 = bx * BM;

    const int r0 = tid >> 2, s0 = tid & 3;
    const int r1 = (tid + 256) >> 2;       // s1 == s0

    floatx4 acc[4][4] = {};

    auto stage = [&](int bsel, int k0) {
        const ushort_t* gA0 = A  + (size_t)(m0 + r0) * K + k0 + s0 * 8;
        const ushort_t* gA1 = A  + (size_t)(m0 + r1) * K + k0 + s0 * 8;
        const ushort_t* gB0 = Bt + (size_t)(n0 + r0) * K + k0 + s0 * 8;
        const ushort_t* gB1 = Bt + (size_t)(n0 + r1) * K + k0 + s0 * 8;
        ushort_t* a = As + bsel * BUF;
        ushort_t* b = Bs + bsel * BUF;
        __builtin_amdgcn_global_load_lds((glb_us*)gA0, (lds_us*)(a + tid * 8),         16, 0, 0);
        __builtin_amdgcn_global_load_lds((glb_us*)gA1, (lds_us*)(a + (tid + 256) * 8), 16, 0, 0);
        __builtin_amdgcn_global_load_lds((glb_us*)gB0, (lds_us*)(b + tid * 8),         16, 0, 0);
        __builtin_amdgcn_global_load_lds((glb_us*)gB1, (lds_us*)(b + (tid + 256) * 8), 16, 0, 0);
    };

    const int nt = K / BK;
    stage(0, 0);
    __syncthreads();

    int cur = 0;
    for (int t = 0; t < nt; ++t) {
        if (t + 1 < nt) stage(cur ^ 1, (t + 1) * BK);

        const ushort_t* a = As + cur * BUF;
        const ushort_t* b = Bs + cur * BUF;
        short8 af[4], bfr[4];
        #pragma unroll
        for (int i = 0; i < 4; i++)
            af[i] = *(const short8*)(a + (wm + i * 16 + ml) * BK + quad * 8);
        #pragma unroll
        for (int j = 0; j < 4; j++)
            bfr[j] = *(const short8*)(b + (wn + j * 16 + ml) * BK + quad * 8);
        #pragma unroll
        for (int i = 0; i < 4; i++)
            #pragma unroll
            for (int j = 0; j < 4; j++)
                acc[i][j] = __builtin_amdgcn_mfma_f32_16x16x32_bf16(
                    af[i], bfr[j], acc[i][j], 0, 0, 0);
        __syncthreads();
        cur ^= 1;
    }

    // Epilogue. D layout: col = lane&15, row = quad*4 + reg.
    if constexpr (OUT_BF16) {
        constexpr int EST = 76;
        ushort_t* wb = As + wave * (16 * EST + 8);
        const int lr  = lane >> 2;
        const int sg  = lane & 3;
        #pragma unroll
        for (int i = 0; i < 4; i++) {
            #pragma unroll
            for (int j = 0; j < 4; j++) {
                int col = n0 + wn + j * 16 + ml;
                float bc = (col < bsplit) ? bias[col] : bias2[col - bsplit];
                #pragma unroll
                for (int r = 0; r < 4; r++) {
                    float v = acc[i][j][r] + bc;
                    if (GELU_ACT) v = gelu_f(v);
                    if (HAS_RES)
                        v += res[(size_t)(m0 + wm + i * 16 + quad * 4 + r) * N
                                 + n0 + wn + j * 16 + ml];
                    wb[(quad * 4 + r) * EST + j * 16 + ml] = f2b(v);
                }
            }
            asm volatile("s_waitcnt lgkmcnt(0)" ::: "memory");
            #pragma unroll
            for (int h = 0; h < 2; h++) {
                int off = lr * EST + (sg + 4 * h) * 8;
                short4v lo = *(const short4v*)(wb + off);
                short4v hi = *(const short4v*)(wb + off + 4);
                short8 vv;
                vv[0] = lo[0]; vv[1] = lo[1]; vv[2] = lo[2]; vv[3] = lo[3];
                vv[4] = hi[0]; vv[5] = hi[1]; vv[6] = hi[2]; vv[7] = hi[3];
                *(short8*)(Cbf + (size_t)(m0 + wm + i * 16 + lr) * N
                                 + n0 + wn + (sg + 4 * h) * 8) = vv;
            }
        }
    } else {
        #pragma unroll
        for (int j = 0; j < 4; j++) {
            int col = n0 + wn + j * 16 + ml;
            float bc = (col < bsplit) ? bias[col] : bias2[col - bsplit];
            #pragma unroll
            for (int i = 0; i < 4; i++) {
                int row = m0 + wm + i * 16 + quad * 4;
                #pragma unroll
                for (int r = 0; r < 4; r++) {
                    float v = acc[i][j][r] + bc;
                    if (GELU_ACT) v = gelu_f(v);
                    if (HAS_RES) v += res[(size_t)(row + r) * N + col];
                    C[(size_t)(row + r) * N + col] = v;
                }
            }
        }
    }
}

// ---------------------------------------------------------------------------
// Standalone GEMM kernel (steps 6, 8, 9) — identical codegen to round 12.
// ---------------------------------------------------------------------------
template<int GELU_ACT, int HAS_RES, int OUT_BF16>
__global__ __launch_bounds__(256) void gemm_mfma(
    const ushort_t* __restrict__ A, const ushort_t* __restrict__ Bt,
    const float* __restrict__ bias, const float* __restrict__ bias2, int bsplit,
    const float* __restrict__ res,
    float* __restrict__ C, ushort_t* __restrict__ Cbf,
    int M, int N, int K, int NX)
{
    __shared__ __align__(16) ushort_t As[2 * 128 * 32];   // 16 KB
    __shared__ __align__(16) ushort_t Bs[2 * 128 * 32];   // 16 KB
    int w = xcd_swizzle(blockIdx.x, gridDim.x);
    gemm_body<GELU_ACT, HAS_RES, OUT_BF16>(
        As, Bs, A, Bt, bias, bias2, bsplit, res, C, Cbf, M, N, K, NX, w);
}

// ---------------------------------------------------------------------------
// Merged steps 2+3+4: one 1700-block dispatch.
//   work id w in [0,680):    value_b = bf16(src_bf @ WvT + bv)      (NX=2)
//   work id w in [680,1700): comb    = q_bf @ [Wof|Wat] + [bof|bat] (NX=3)
// Both consume only step-1 outputs and write disjoint buffers -> safe to
// co-schedule; tails/heads of the two jobs interleave on the CU pool
// (removes one launch boundary + grid-drain bubble).
// ---------------------------------------------------------------------------
__global__ __launch_bounds__(256) void gemm_qkv(
    const ushort_t* __restrict__ src_bf, const ushort_t* __restrict__ WvT,
    const float* __restrict__ bv, ushort_t* __restrict__ value_b,
    const ushort_t* __restrict__ q_bf, const ushort_t* __restrict__ WofT,
    const float* __restrict__ bof, const float* __restrict__ bat,
    float* __restrict__ comb, int M)
{
    __shared__ __align__(16) ushort_t As[2 * 128 * 32];   // 16 KB
    __shared__ __align__(16) ushort_t Bs[2 * 128 * 32];   // 16 KB
    int w = xcd_swizzle(blockIdx.x, gridDim.x);
    if (w < 2 * (MROWS / 128)) {
        gemm_body<0, 0, 1>(As, Bs, src_bf, WvT, bv, bv, 1 << 30, nullptr,
                           nullptr, value_b, M, 256, 256, 2, w);
    } else {
        gemm_body<0, 0, 0>(As, Bs, q_bf, WofT, bof, bat, 256, nullptr,
                           comb, nullptr, M, 384, 256, 3, w - 2 * (MROWS / 128));
    }
}

// ---------------------------------------------------------------------------
// Fused softmax + multi-scale deformable bilinear sampling, v7 (VERIFIED
// 95.2 us @ VALUBusy ~100% — DS 64->26 confirmed the DS-pipe theory).
// Unchanged (control dispatch).
// ---------------------------------------------------------------------------
__global__ __launch_bounds__(256) void msdeform_kernel(
    const ushort_t* __restrict__ value, const float* __restrict__ comb,
    const float* __restrict__ refp, ushort_t* __restrict__ out_bf)
{
    int blk = xcd_swizzle(blockIdx.x, gridDim.x);
    int gid = blk * 8 + (threadIdx.x >> 5);  // (b*LEN + q)*8 + m
    int l   = threadIdx.x & 31;
    int bq  = gid >> 3;
    int m   = gid & 7;
    int b   = (bq >= LEN_TOT) ? 1 : 0;

    // ---- softmax over 16 logits via DPP rotation-reduce (rows of 16)
    int i = l & 15;
    float logit = comb[(size_t)bq * 384 + 256 + m * 16 + i];
    float mx = logit;
    mx = fmaxf(mx, dpp_f<0x128>(mx));
    mx = fmaxf(mx, dpp_f<0x124>(mx));
    mx = fmaxf(mx, dpp_f<0x122>(mx));
    mx = fmaxf(mx, dpp_f<0x121>(mx));
    float e = __expf(logit - mx);
    float se = e;
    se += dpp_f<0x128>(se);
    se += dpp_f<0x124>(se);
    se += dpp_f<0x122>(se);
    se += dpp_f<0x121>(se);
    float prob = e / se;

    const int ST_[4] = {0, 16384, 20480, 21504};
    const int sA = (l >> 2) & 7;
    const int cA = l & 3;
    const int dx = cA & 1, dy = cA >> 1;
    float probA = __shfl(prob, sA, 32);
    float probB = __shfl(prob, sA + 8, 32);

    int aA, aB; float hA, hB;
    #define CORNER(S, PROB, ADDR, WGT) { \
        int lvl = (S) >> 2; \
        int Wl = 128 >> lvl; float Wf = (float)Wl; \
        float2 off2 = ((const float2*)comb)[(size_t)bq * 192 + m * 16 + (S)]; \
        float2 ref2 = ((const float2*)refp)[(size_t)bq * 4 + lvl]; \
        float xs = fmaf(ref2.x, Wf, off2.x) - 0.5f; \
        float ys = fmaf(ref2.y, Wf, off2.y) - 0.5f; \
        float xf = floorf(xs), yf = floorf(ys); \
        int x0 = (int)xf, y0 = (int)yf; \
        float wx = xs - xf, wy = ys - yf; \
        int xc = x0 + dx, yc = y0 + dy; \
        bool v = (xc >= 0) & (xc < Wl) & (yc >= 0) & (yc < Wl); \
        int cx = min(max(xc, 0), Wl - 1); \
        int cy = min(max(yc, 0), Wl - 1); \
        ADDR = (b * LEN_TOT + ST_[lvl] + cy * Wl + cx) * 512 + m * 64; \
        float wxe = dx ? wx : 1.0f - wx; \
        float wye = dy ? wy : 1.0f - wy; \
        WGT = v ? (PROB) * wxe * wye : 0.0f; }
    CORNER(sA,     probA, aA, hA)
    CORNER(sA + 8, probB, aB, hB)
    #undef CORNER

    const int cl2 = l >> 2;
    const int dof = (l & 3) * 16;

    int p0 = __shfl(aA,      cl2, 32) + dof;
    int p1 = __shfl(aA,  8 + cl2, 32) + dof;
    int p2 = __shfl(aA, 16 + cl2, 32) + dof;
    int p3 = __shfl(aA, 24 + cl2, 32) + dof;
    int p4 = __shfl(aB,      cl2, 32) + dof;
    int p5 = __shfl(aB,  8 + cl2, 32) + dof;
    int p6 = __shfl(aB, 16 + cl2, 32) + dof;
    int p7 = __shfl(aB, 24 + cl2, 32) + dof;
    float h0 = __shfl(hA,      cl2, 32);
    float h1 = __shfl(hA,  8 + cl2, 32);
    float h2 = __shfl(hA, 16 + cl2, 32);
    float h3 = __shfl(hA, 24 + cl2, 32);
    float h4 = __shfl(hB,      cl2, 32);
    float h5 = __shfl(hB,  8 + cl2, 32);
    float h6 = __shfl(hB, 16 + cl2, 32);
    float h7 = __shfl(hB, 24 + cl2, 32);

    const char* vb = (const char*)value;
    uint4 v0 = *(const uint4*)(vb + p0);
    uint4 v1 = *(const uint4*)(vb + p1);
    uint4 v2 = *(const uint4*)(vb + p2);
    uint4 v3 = *(const uint4*)(vb + p3);
    uint4 v4 = *(const uint4*)(vb + p4);
    uint4 v5 = *(const uint4*)(vb + p5);
    uint4 v6 = *(const uint4*)(vb + p6);
    uint4 v7 = *(const uint4*)(vb + p7);

    float c0 = 0, c1 = 0, c2 = 0, c3 = 0, c4 = 0, c5 = 0, c6 = 0, c7 = 0;
    #define ACC8(V, H) \
        c0 = fmaf(H, __uint_as_float((V).x << 16),         c0); \
        c1 = fmaf(H, __uint_as_float((V).x & 0xffff0000u), c1); \
        c2 = fmaf(H, __uint_as_float((V).y << 16),         c2); \
        c3 = fmaf(H, __uint_as_float((V).y & 0xffff0000u), c3); \
        c4 = fmaf(H, __uint_as_float((V).z << 16),         c4); \
        c5 = fmaf(H, __uint_as_float((V).z & 0xffff0000u), c5); \
        c6 = fmaf(H, __uint_as_float((V).w << 16),         c6); \
        c7 = fmaf(H, __uint_as_float((V).w & 0xffff0000u), c7);
    ACC8(v0, h0) ACC8(v1, h1) ACC8(v2, h2) ACC8(v3, h3)
    ACC8(v4, h4) ACC8(v5, h5) ACC8(v6, h6) ACC8(v7, h7)
    #undef ACC8

    c0 += dpp_f<0x124>(c0); c1 += dpp_f<0x124>(c1);
    c2 += dpp_f<0x124>(c2); c3 += dpp_f<0x124>(c3);
    c4 += dpp_f<0x124>(c4); c5 += dpp_f<0x124>(c5);
    c6 += dpp_f<0x124>(c6); c7 += dpp_f<0x124>(c7);
    c0 += dpp_f<0x128>(c0); c1 += dpp_f<0x128>(c1);
    c2 += dpp_f<0x128>(c2); c3 += dpp_f<0x128>(c3);
    c4 += dpp_f<0x128>(c4); c5 += dpp_f<0x128>(c5);
    c6 += dpp_f<0x128>(c6); c7 += dpp_f<0x128>(c7);
    c0 += swz16_f(c0); c1 += swz16_f(c1);
    c2 += swz16_f(c2); c3 += swz16_f(c3);
    c4 += swz16_f(c4); c5 += swz16_f(c5);
    c6 += swz16_f(c6); c7 += swz16_f(c7);

    if (l < 4) {
        short8 ov;
        ov[0] = (short)f2b(c0); ov[1] = (short)f2b(c1);
        ov[2] = (short)f2b(c2); ov[3] = (short)f2b(c3);
        ov[4] = (short)f2b(c4); ov[5] = (short)f2b(c5);
        ov[6] = (short)f2b(c6); ov[7] = (short)f2b(c7);
        *(short8*)(out_bf + (size_t)gid * 32 + l * 8) = ov;
    }
}

// ---------------------------------------------------------------------------
// kernel_launch — workspace layout (round-2 verified):
//   [q_bf | value(bf16, region sized f32) | src_bf | comb | weights]
//   h1_bf == src_bf..(spans src_bf + comb regions exactly, all dead by then)
// ---------------------------------------------------------------------------
extern "C" void kernel_launch(void* const* d_in, const int* in_sizes, int n_in,
                              void* d_out, int out_size, void* d_ws, size_t ws_size,
                              hipStream_t stream)
{
    const float* src  = (const float*)d_in[0];
    const float* pos  = (const float*)d_in[1];
    const float* refp = (const float*)d_in[2];
    const float* n1g = (const float*)d_in[5];
    const float* n1b = (const float*)d_in[6];
    const float* n2g = (const float*)d_in[7];
    const float* n2b = (const float*)d_in[8];
    const float* Wv  = (const float*)d_in[9];
    const float* bv  = (const float*)d_in[10];
    const float* Wof = (const float*)d_in[11];
    const float* bof = (const float*)d_in[12];
    const float* Wat = (const float*)d_in[13];
    const float* bat = (const float*)d_in[14];
    const float* Wo  = (const float*)d_in[15];
    const float* bo  = (const float*)d_in[16];
    const float* Wf1 = (const float*)d_in[17];
    const float* bf1 = (const float*)d_in[18];
    const float* Wf2 = (const float*)d_in[19];
    const float* bf2 = (const float*)d_in[20];
    float* out = (float*)d_out;

    char* ws = (char*)d_ws;
    const int M = MROWS;               // 43520
    const size_t SZ_BF = (size_t)M * 256 * 2;   // 22,282,240
    const size_t SZ_F  = (size_t)M * 256 * 4;   // 44,564,480
    const int BIG = 1 << 30;

    ushort_t* q_bf    = (ushort_t*)(ws);                              // [M,256] bf16
    ushort_t* value_b = (ushort_t*)(ws + SZ_BF);                      // [M,256] bf16 (region sized SZ_F)
    ushort_t* src_bf  = (ushort_t*)(ws + SZ_BF + SZ_F);               // [M,256] bf16
    float*    comb    = (float*)   (ws + 2 * SZ_BF + SZ_F);           // [M,384] f32 (offs | logits)
    ushort_t* h0_bf   = q_bf;
    ushort_t* sampled = src_bf;
    float*    src2    = (float*)   (ws + SZ_BF);                      // overwrites value_b after step 5
    ushort_t* h1_bf   = src_bf;   // [M,1024] bf16, spans src_bf + comb exactly
    char* wtp = ws + 2 * SZ_BF + 2 * SZ_F + (size_t)M * 128 * 4;
    ushort_t* WvT  = (ushort_t*)(wtp);
    ushort_t* WofT = WvT  + 256 * 256;   // [256][256]
    ushort_t* WatT = WofT + 256 * 256;   // [128][256]  (contiguous => [384][256])
    ushort_t* WoT  = WatT + 256 * 128;
    ushort_t* Wf1T = WoT  + 256 * 256;
    ushort_t* Wf2T = Wf1T + 256 * 1024;

    // 0) transpose+convert all weights to [N][K] bf16
    TP tp;
    tp.s[0] = Wv;  tp.d[0] = WvT;  tp.K[0] = 256;  tp.N[0] = 256;
    tp.s[1] = Wof; tp.d[1] = WofT; tp.K[1] = 256;  tp.N[1] = 256;
    tp.s[2] = Wat; tp.d[2] = WatT; tp.K[2] = 256;  tp.N[2] = 128;
    tp.s[3] = Wo;  tp.d[3] = WoT;  tp.K[3] = 256;  tp.N[3] = 256;
    tp.s[4] = Wf1; tp.d[4] = Wf1T; tp.K[4] = 256;  tp.N[4] = 1024;
    tp.s[5] = Wf2; tp.d[5] = Wf2T; tp.K[5] = 1024; tp.N[5] = 256;
    tp.start[0] = 0;   tp.start[1] = 64;  tp.start[2] = 128;
    tp.start[3] = 160; tp.start[4] = 224; tp.start[5] = 480; tp.start[6] = 736;
    transpose_convert<<<736, 256, 0, stream>>>(tp);

    // 1) q_bf = bf16(LN1(src) + pos); src_bf = bf16(src)
    ln_dual_kernel<<<M / 4, 256, 0, stream>>>(src, n1g, n1b, pos, q_bf, src_bf);
    // 2+3+4 merged) value_b = bf16(src_bf @ Wv + bv);
    //               comb    = q_bf @ [Wof|Wat] + [bof|bat]
    gemm_qkv<<<5 * (M / 128), 256, 0, stream>>>(
        src_bf, WvT, bv, value_b, q_bf, WofT, bof, bat, comb, M);
    // 5) fused softmax + sampling -> sampled (bf16; comb dead after)
    msdeform_kernel<<<M, 256, 0, stream>>>(value_b, comb, refp, sampled);
    // 6) src2 = sampled @ Wo + bo + src  (fp32, overwrites value_b)
    gemm_mfma<0, 1, 0><<<2 * (M / 128), 256, 0, stream>>>(
        sampled, WoT, bo, bo, BIG, src, src2, nullptr, M, 256, 256, 2);
    // 7) h0_bf = bf16(LN2(src2))
    ln_dual_kernel<<<M / 4, 256, 0, stream>>>(src2, n2g, n2b, nullptr, h0_bf, nullptr);
    // 8) h1_bf = bf16(gelu(h0_bf @ Wf1 + bf1))  (overlays sampled+comb, all dead)
    gemm_mfma<1, 0, 1><<<8 * (M / 128), 256, 0, stream>>>(
        h0_bf, Wf1T, bf1, bf1, BIG, nullptr, nullptr, h1_bf, M, 1024, 256, 8);
    // 9) out = h1_bf @ Wf2 + bf2 + src2  (fp32)
    gemm_mfma<0, 1, 0><<<2 * (M / 128), 256, 0, stream>>>(
        h1_bf, Wf2T, bf2, bf2, BIG, src2, out, nullptr, M, 256, 1024, 2);
}